// Round 3
// baseline (331.533 us; speedup 1.0000x reference)
//
#include <hip/hip_runtime.h>
#include <hip/hip_bf16.h>

#define N_NODES 50000
#define N_EDGES 800000
#define D_IN 128
#define D_HID 512
#define D_OUT 128
#define CAT_DIM 640   // D_IN + D_HID
#define CAP 64        // per-node edge-bucket capacity (Poisson(16): P(>=64) ~ 1e-20)

typedef __attribute__((ext_vector_type(8))) short short8;
typedef __attribute__((ext_vector_type(4))) float floatx4;

__device__ __forceinline__ unsigned short f2bf(float f) {
    unsigned u = __float_as_uint(f);
    unsigned r = u + 0x7fffu + ((u >> 16) & 1u);   // RNE
    return (unsigned short)(r >> 16);
}

// ================= prep: casts/transposes/deg-zero/dtype-detect ============

#define PREP_CASTX_BLOCKS   6250   // 50000*32 threads / 256
#define PREP_FCW_BLOCKS      256   // 128*512 / 256
#define PREP_W2_BLOCKS       320   // 640*128 / 256
#define PREP_DEG_BLOCKS      196   // ceil(50000/256)
#define PREP_TOTAL_BLOCKS  (PREP_CASTX_BLOCKS + PREP_FCW_BLOCKS + PREP_W2_BLOCKS + PREP_DEG_BLOCKS + 1)

__global__ void prep_kernel(const float* __restrict__ X, const float* __restrict__ fcW,
                            const float* __restrict__ Wm, const int* __restrict__ adj,
                            unsigned short* __restrict__ concat,
                            unsigned short* __restrict__ fcwT,
                            unsigned short* __restrict__ WT,
                            int* __restrict__ deg, int* __restrict__ flag) {
    int b = blockIdx.x;
    int tid = threadIdx.x;
    if (b < PREP_CASTX_BLOCKS) {
        int t = b * 256 + tid;                 // 50000*32
        int row = t >> 5;
        int cg2 = (t & 31) * 4;
        float4 v = *(const float4*)(X + (size_t)row * D_IN + cg2);
        unsigned short o[4] = { f2bf(v.x), f2bf(v.y), f2bf(v.z), f2bf(v.w) };
        *(unsigned long long*)(concat + (size_t)row * CAT_DIM + cg2) = *(unsigned long long*)o;
        return;
    }
    b -= PREP_CASTX_BLOCKS;
    if (b < PREP_FCW_BLOCKS) {
        int idx = b * 256 + tid;               // 128*512
        int k = idx >> 9;
        int n = idx & (D_HID - 1);
        fcwT[n * D_IN + k] = f2bf(fcW[idx]);
        return;
    }
    b -= PREP_FCW_BLOCKS;
    if (b < PREP_W2_BLOCKS) {
        int idx = b * 256 + tid;               // 640*128
        int k = idx >> 7;
        int n = idx & (D_OUT - 1);
        WT[n * CAT_DIM + k] = f2bf(Wm[idx]);
        return;
    }
    b -= PREP_W2_BLOCKS;
    if (b < PREP_DEG_BLOCKS) {
        int idx = b * 256 + tid;
        if (idx < N_NODES) deg[idx] = 0;
        return;
    }
    // detect (wave 0): int64 high words all zero (node ids < 2^31)
    if (tid < 64) {
        int v = adj[2 * tid + 1];
        unsigned long long m = __ballot(v != 0);
        if (tid == 0) *flag = (m == 0ULL) ? 2 : 1;   // 2 => int64 stride
    }
}

// ================= hist (device fn, used in fused mid kernel) ==============

__device__ __forceinline__ void hist_edges(const int* __restrict__ adj, int s, int e0,
                                           int* __restrict__ deg, int* __restrict__ edge_list) {
    int src0, src1, trg0, trg1;
    if (s == 2) {   // int64: edges e0,e0+1 -> adj dwords [2e0 .. 2e0+3], coalesced
        int4 vs = *(const int4*)(adj + 2 * (size_t)e0);
        int4 vt = *(const int4*)(adj + 2 * ((size_t)N_EDGES + e0));
        src0 = vs.x; src1 = vs.z;
        trg0 = vt.x; trg1 = vt.z;
    } else {        // int32
        int2 vs = *(const int2*)(adj + e0);
        int2 vt = *(const int2*)(adj + N_EDGES + e0);
        src0 = vs.x; src1 = vs.y;
        trg0 = vt.x; trg1 = vt.y;
    }
    int p0 = atomicAdd(&deg[src0], 1);
    if (p0 < CAP) edge_list[src0 * CAP + p0] = trg0;
    int p1 = atomicAdd(&deg[src1], 1);
    if (p1 < CAP) edge_list[src1 * CAP + p1] = trg1;
}

// ================= GEMM1: direct-register MFMA, no LDS, no barriers ========
// K = D_IN = 128 is tiny: stage nothing. Per wave, A-fragments come straight
// from concat (bf16, 16 B/lane coalesced within 16-lane groups) and
// B-fragments from fcwT (128 KB total -> L2-resident across all blocks).
// BM=64, BN=256, 4 waves (2x2), wave-tile 32x128, acc[2][8] = 64 VGPR.
// A logical traffic: 25.6 MB (2 col-tiles); B: L2; F write: 51.2 MB.
// vs old LDS tile: removes 2 barriers/K-step, 3128->1564 blocks, A 51->26 MB.

__device__ __forceinline__ void gemm1_direct(
    const unsigned short* __restrict__ A,    // concat [N_NODES][CAT_DIM], X half
    const unsigned short* __restrict__ Bt,   // fcwT [D_HID][D_IN]
    const float* __restrict__ bias,
    unsigned short* __restrict__ F,
    int bm, int bn)
{
    int tid = threadIdx.x;
    int lane = tid & 63, w = tid >> 6;
    int wm = (w >> 1) * 32, wn = (w & 1) * 128;
    int q = lane >> 4, l16 = lane & 15;
    floatx4 acc[2][8] = {};
    int ar[2];
    #pragma unroll
    for (int mi = 0; mi < 2; ++mi) {
        int r = bm + wm + mi * 16 + l16;
        ar[mi] = r < N_NODES ? r : N_NODES - 1;   // clamp: OOB rows read row 49999, write-guarded below
    }
    #pragma unroll 2
    for (int ks = 0; ks < D_IN / 32; ++ks) {     // 4 K-steps of 32
        short8 af[2], bf[8];
        #pragma unroll
        for (int mi = 0; mi < 2; ++mi)
            af[mi] = *(const short8*)(A + (size_t)ar[mi] * CAT_DIM + ks * 32 + q * 8);
        #pragma unroll
        for (int ni = 0; ni < 8; ++ni)
            bf[ni] = *(const short8*)(Bt + (size_t)(bn + wn + ni * 16 + l16) * D_IN + ks * 32 + q * 8);
        #pragma unroll
        for (int mi = 0; mi < 2; ++mi)
            #pragma unroll
            for (int ni = 0; ni < 8; ++ni)
                acc[mi][ni] = __builtin_amdgcn_mfma_f32_16x16x32_bf16(af[mi], bf[ni], acc[mi][ni], 0, 0, 0);
    }
    #pragma unroll
    for (int mi = 0; mi < 2; ++mi)
        #pragma unroll
        for (int ni = 0; ni < 8; ++ni)
            #pragma unroll
            for (int r = 0; r < 4; ++r) {
                int row = bm + wm + mi * 16 + q * 4 + r;
                int col = bn + wn + ni * 16 + l16;
                if (row < N_NODES) {
                    float v = fmaxf(acc[mi][ni][r] + bias[col], 0.0f);
                    F[(size_t)row * D_HID + col] = f2bf(v);
                }
            }
}

// ================= bf16 MFMA GEMM tile (GEMM2 only): BM=64,BN=128,BK=64 ====

#define GPAD 8
#define SM64_BYTES ((64 + 128) * (64 + GPAD) * 2)

template<int BIAS_RELU, int OUT_BF16>
__device__ __forceinline__ void gemm_tile64(char* smem,
    const unsigned short* __restrict__ A, int lda,
    const unsigned short* __restrict__ Bt, int ldb,
    const float* __restrict__ bias, void* __restrict__ Cout, int ldc,
    int M, int K, int bm, int bn)
{
    constexpr int BK = 64;
    typedef unsigned short Row[BK + GPAD];
    Row* As = (Row*)smem;
    Row* Bs = (Row*)(smem + 64 * (BK + GPAD) * 2);
    int tid = threadIdx.x;
    int lane = tid & 63, w = tid >> 6;
    int wm = (w >> 1) * 32, wn = (w & 1) * 64;
    int q = lane >> 4, l16 = lane & 15;
    floatx4 acc[2][4] = {};
    int ra = tid >> 2;            // A row 0..63
    int ca = (tid & 3) * 8;       // A col base; passes +0,+32
    int rb = tid >> 1;            // B row 0..127
    int cb = (tid & 1) * 8;       // B col base; passes +0,+16,+32,+48

    for (int k0 = 0; k0 < K; k0 += BK) {
        {
            int gr = bm + ra;
            const unsigned short* ap = A + (size_t)gr * lda + k0 + ca;
            #pragma unroll
            for (int p = 0; p < 2; ++p) {
                uint4 va = make_uint4(0u, 0u, 0u, 0u);
                if (gr < M) va = *(const uint4*)(ap + p * 32);
                *(uint4*)(&As[ra][ca + p * 32]) = va;
            }
        }
        {
            const unsigned short* bp = Bt + (size_t)(bn + rb) * ldb + k0 + cb;
            #pragma unroll
            for (int p = 0; p < 4; ++p)
                *(uint4*)(&Bs[rb][cb + p * 16]) = *(const uint4*)(bp + p * 16);
        }
        __syncthreads();
        #pragma unroll
        for (int ks = 0; ks < 2; ++ks) {
            short8 af[2], bf[4];
            #pragma unroll
            for (int mi = 0; mi < 2; ++mi)
                af[mi] = *(const short8*)(&As[wm + mi * 16 + l16][ks * 32 + q * 8]);
            #pragma unroll
            for (int ni = 0; ni < 4; ++ni)
                bf[ni] = *(const short8*)(&Bs[wn + ni * 16 + l16][ks * 32 + q * 8]);
            #pragma unroll
            for (int mi = 0; mi < 2; ++mi)
                #pragma unroll
                for (int ni = 0; ni < 4; ++ni)
                    acc[mi][ni] = __builtin_amdgcn_mfma_f32_16x16x32_bf16(af[mi], bf[ni], acc[mi][ni], 0, 0, 0);
        }
        __syncthreads();
    }

    #pragma unroll
    for (int mi = 0; mi < 2; ++mi) {
        #pragma unroll
        for (int ni = 0; ni < 4; ++ni) {
            #pragma unroll
            for (int r = 0; r < 4; ++r) {
                int row = bm + wm + mi * 16 + q * 4 + r;
                int col = bn + wn + ni * 16 + l16;
                if (row < M) {
                    float v = acc[mi][ni][r];
                    if (BIAS_RELU) v = fmaxf(v + bias[col], 0.0f);
                    if (OUT_BF16) ((unsigned short*)Cout)[(size_t)row * ldc + col] = f2bf(v);
                    else          ((float*)Cout)[(size_t)row * ldc + col] = v;
                }
            }
        }
    }
}

// ================= fused mid: hist blocks + GEMM1 blocks ===================

#define HIST_VB     1563   // ceil((N_EDGES/2)/256)
#define GEMM1_MT     782   // ceil(50000/64)
#define GEMM1_TILES (GEMM1_MT * 2)   // BN=256 -> 2 col-tiles

__global__ __launch_bounds__(256)
void mid_kernel(const int* __restrict__ adj, const int* __restrict__ flag,
                int* __restrict__ deg, int* __restrict__ edge_list,
                const unsigned short* __restrict__ concat,
                const unsigned short* __restrict__ fcwT,
                const float* __restrict__ fcb,
                unsigned short* __restrict__ F) {
    if (blockIdx.x < HIST_VB) {
        int e0 = (blockIdx.x * 256 + threadIdx.x) * 2;
        if (e0 < N_EDGES) hist_edges(adj, flag[0], e0, deg, edge_list);
        return;
    }
    int tile = blockIdx.x - HIST_VB;
    gemm1_direct(concat, fcwT, fcb, F, (tile >> 1) * 64, (tile & 1) * 256);
}

// ================= aggregate: wave per node (R0 form, measured 114 us) =====
// R1/R2 evidence: gather saturates an L3->L2 service-rate ceiling (~3.7 TB/s
// fetch) already at this shape; deeper unroll (R2) and LDS fusion (R1) both
// regressed. Do not touch.

__device__ __forceinline__ void fmax_bf16x8(float* acc, const uint4& p) {
    const unsigned* a = (const unsigned*)&p;
    #pragma unroll
    for (int j = 0; j < 4; ++j) {
        unsigned u = a[j];
        acc[2 * j]     = fmaxf(acc[2 * j],     __uint_as_float(u << 16));
        acc[2 * j + 1] = fmaxf(acc[2 * j + 1], __uint_as_float(u & 0xffff0000u));
    }
}

__global__ __launch_bounds__(256)
void aggregate_kernel(const unsigned short* __restrict__ F,
                      const int* __restrict__ deg,
                      const int* __restrict__ edge_list,
                      unsigned short* __restrict__ concat) {
    int gw = (blockIdx.x * 256 + threadIdx.x) >> 6;
    if (gw >= N_NODES) return;
    int lane = threadIdx.x & 63;
    int d = deg[gw];
    d = d < CAP ? d : CAP;
    const int* el = edge_list + gw * CAP;
    float acc[8] = {0.f, 0.f, 0.f, 0.f, 0.f, 0.f, 0.f, 0.f};
    int i = 0;
    for (; i + 2 <= d; i += 2) {
        int t0 = el[i], t1 = el[i + 1];
        uint4 p0 = *(const uint4*)(F + (size_t)t0 * D_HID + lane * 8);
        uint4 p1 = *(const uint4*)(F + (size_t)t1 * D_HID + lane * 8);
        fmax_bf16x8(acc, p0);
        fmax_bf16x8(acc, p1);
    }
    if (i < d) {
        uint4 p0 = *(const uint4*)(F + (size_t)el[i] * D_HID + lane * 8);
        fmax_bf16x8(acc, p0);
    }
    unsigned out[4];
    #pragma unroll
    for (int j = 0; j < 4; ++j) {
        unsigned lo = __float_as_uint(acc[2 * j]) >> 16;          // exact: maxima of bf16 values
        unsigned hi = __float_as_uint(acc[2 * j + 1]) & 0xffff0000u;
        out[j] = lo | hi;
    }
    *(uint4*)(concat + (size_t)gw * CAT_DIM + D_IN + lane * 8) = *(uint4*)out;
}

// ================= GEMM2 ===================================================

__global__ __launch_bounds__(256)
void gemm2_kernel(const unsigned short* __restrict__ concat,
                  const unsigned short* __restrict__ WT,
                  float* __restrict__ out) {
    __shared__ char smem[SM64_BYTES];
    gemm_tile64<0, 0>(smem, concat, CAT_DIM, WT, CAT_DIM, nullptr, out, D_OUT,
                      N_NODES, CAT_DIM, blockIdx.x * 64, 0);
}

// ================= host launch =============================================

extern "C" void kernel_launch(void* const* d_in, const int* in_sizes, int n_in,
                              void* d_out, int out_size, void* d_ws, size_t ws_size,
                              hipStream_t stream) {
    const float* X    = (const float*)d_in[0];
    const float* fc_w = (const float*)d_in[1];
    const float* fc_b = (const float*)d_in[2];
    const float* Wm   = (const float*)d_in[3];
    const int*   adj  = (const int*)d_in[4];
    float* outp = (float*)d_out;

    char* ws = (char*)d_ws;
    size_t off = 0;
    auto alloc = [&](size_t bytes) -> void* {
        void* p = ws + off;
        off = (off + bytes + 255) & ~(size_t)255;
        return p;
    };
    unsigned short* concat = (unsigned short*)alloc((size_t)N_NODES * CAT_DIM * 2);
    unsigned short* F      = (unsigned short*)alloc((size_t)N_NODES * D_HID * 2);
    unsigned short* fcwT   = (unsigned short*)alloc((size_t)D_HID * D_IN * 2);
    unsigned short* WT     = (unsigned short*)alloc((size_t)D_OUT * CAT_DIM * 2);
    int* deg       = (int*)alloc((size_t)N_NODES * 4);
    int* edge_list = (int*)alloc((size_t)N_NODES * CAP * 4);
    int* flag      = (int*)alloc(256);

    prep_kernel<<<PREP_TOTAL_BLOCKS, 256, 0, stream>>>(X, fc_w, Wm, adj, concat, fcwT, WT, deg, flag);
    mid_kernel<<<HIST_VB + GEMM1_TILES, 256, 0, stream>>>(adj, flag, deg, edge_list,
                                                          concat, fcwT, fc_b, F);
    aggregate_kernel<<<(N_NODES * 64) / 256, 256, 0, stream>>>(F, deg, edge_list, concat);
    gemm2_kernel<<<GEMM1_MT, 256, 0, stream>>>(concat, WT, outp);
}

// Round 4
// 321.343 us; speedup vs baseline: 1.0317x; 1.0317x over previous
//
#include <hip/hip_runtime.h>
#include <hip/hip_bf16.h>

#define N_NODES 50000
#define N_EDGES 800000
#define D_IN 128
#define D_HID 512
#define D_OUT 128
#define CAT_DIM 640   // D_IN + D_HID
#define CAP 64        // per-node edge-bucket capacity (Poisson(16): P(>=64) ~ 1e-20)

typedef __attribute__((ext_vector_type(8))) short short8;
typedef __attribute__((ext_vector_type(4))) float floatx4;

__device__ __forceinline__ unsigned short f2bf(float f) {
    unsigned u = __float_as_uint(f);
    unsigned r = u + 0x7fffu + ((u >> 16) & 1u);   // RNE
    return (unsigned short)(r >> 16);
}

// ================= hist (device fn) ========================================

__device__ __forceinline__ void hist_edges(const int* __restrict__ adj, int s, int e0,
                                           int* __restrict__ deg, int* __restrict__ edge_list) {
    int src0, src1, trg0, trg1;
    if (s == 2) {   // int64: edges e0,e0+1 -> adj dwords [2e0 .. 2e0+3], coalesced
        int4 vs = *(const int4*)(adj + 2 * (size_t)e0);
        int4 vt = *(const int4*)(adj + 2 * ((size_t)N_EDGES + e0));
        src0 = vs.x; src1 = vs.z;
        trg0 = vt.x; trg1 = vt.z;
    } else {        // int32
        int2 vs = *(const int2*)(adj + e0);
        int2 vt = *(const int2*)(adj + N_EDGES + e0);
        src0 = vs.x; src1 = vs.y;
        trg0 = vt.x; trg1 = vt.y;
    }
    int p0 = atomicAdd(&deg[src0], 1);
    if (p0 < CAP) edge_list[src0 * CAP + p0] = trg0;
    int p1 = atomicAdd(&deg[src1], 1);
    if (p1 < CAP) edge_list[src1 * CAP + p1] = trg1;
}

// ================= fused prep + hist =======================================
// hist (needs only adj + zeroed deg) is independent of the casts/transposes:
// fuse as disjoint block ranges, hist FIRST so its latency-bound scatter
// overlaps the BW-bound cast blocks. deg is zeroed by hipMemsetAsync before
// this kernel. int64-vs-int32 detect is a per-wave ballot over the same 64
// L2-hot adj entries (no flag buffer, no cross-kernel dependency).

#define HIST_BLOCKS         1563   // ceil((N_EDGES/2)/256)
#define PREP_CASTX_BLOCKS   6250   // 50000*32 threads / 256
#define PREP_FCW_BLOCKS      256   // 128*512 / 256
#define PREP_W2_BLOCKS       320   // 640*128 / 256
#define FUSED1_BLOCKS (HIST_BLOCKS + PREP_CASTX_BLOCKS + PREP_FCW_BLOCKS + PREP_W2_BLOCKS)

__global__ void prep_hist_kernel(const float* __restrict__ X, const float* __restrict__ fcW,
                                 const float* __restrict__ Wm, const int* __restrict__ adj,
                                 unsigned short* __restrict__ concat,
                                 unsigned short* __restrict__ fcwT,
                                 unsigned short* __restrict__ WT,
                                 int* __restrict__ deg, int* __restrict__ edge_list) {
    int b = blockIdx.x;
    int tid = threadIdx.x;
    if (b < HIST_BLOCKS) {
        // per-wave dtype detect: int64 iff high dwords of first 64 ids all zero
        int v = adj[2 * (tid & 63) + 1];
        int s = (__ballot(v != 0) == 0ULL) ? 2 : 1;
        int e0 = (b * 256 + tid) * 2;
        if (e0 < N_EDGES) hist_edges(adj, s, e0, deg, edge_list);
        return;
    }
    b -= HIST_BLOCKS;
    if (b < PREP_CASTX_BLOCKS) {
        int t = b * 256 + tid;                 // 50000*32
        int row = t >> 5;
        int cg2 = (t & 31) * 4;
        float4 v = *(const float4*)(X + (size_t)row * D_IN + cg2);
        unsigned short o[4] = { f2bf(v.x), f2bf(v.y), f2bf(v.z), f2bf(v.w) };
        *(unsigned long long*)(concat + (size_t)row * CAT_DIM + cg2) = *(unsigned long long*)o;
        return;
    }
    b -= PREP_CASTX_BLOCKS;
    if (b < PREP_FCW_BLOCKS) {
        int idx = b * 256 + tid;               // 128*512
        int k = idx >> 9;
        int n = idx & (D_HID - 1);
        fcwT[n * D_IN + k] = f2bf(fcW[idx]);
        return;
    }
    b -= PREP_FCW_BLOCKS;
    {
        int idx = b * 256 + tid;               // 640*128
        int k = idx >> 7;
        int n = idx & (D_OUT - 1);
        WT[n * CAT_DIM + k] = f2bf(Wm[idx]);
    }
}

// ================= GEMM1: single-stage A, B-chunk loop (K=128, no K-loop) ==
// BM=64, full N=512 per block. A-tile staged ONCE (read once from HBM:
// 12.8 MB total vs 51.2 MB with 4x col-tile redundancy). B chunks of 128
// cols staged from L2-resident fcwT (128 KB). LDS 52224 B -> 3 blocks/CU.
// Row stride 136 elem = 272 B: fragment reads are 2-way bank-aliased (free).

#define G1_PAD 8

__global__ __launch_bounds__(256)
void gemm1_kernel(const unsigned short* __restrict__ concat,
                  const unsigned short* __restrict__ fcwT,
                  const float* __restrict__ fcb,
                  unsigned short* __restrict__ F) {
    __shared__ unsigned short As[64][D_IN + G1_PAD];
    __shared__ unsigned short Bs[128][D_IN + G1_PAD];
    int tid = threadIdx.x;
    int lane = tid & 63, w = tid >> 6;
    int bm = blockIdx.x * 64;
    {   // stage A once: 4 passes x (16 rows x 128 cols)
        int r = tid >> 4;
        int c = (tid & 15) * 8;
        #pragma unroll
        for (int p = 0; p < 4; ++p) {
            int row = r + p * 16;
            int gr = bm + row;
            uint4 v = make_uint4(0u, 0u, 0u, 0u);
            if (gr < N_NODES) v = *(const uint4*)(concat + (size_t)gr * CAT_DIM + c);
            *(uint4*)(&As[row][c]) = v;
        }
    }
    int wm = (w >> 1) * 32, wn = (w & 1) * 64;
    int q = lane >> 4, l16 = lane & 15;
    for (int nc = 0; nc < 4; ++nc) {
        {   // stage B chunk: fcwT rows [nc*128, nc*128+128)
            int r = tid >> 4;
            int c = (tid & 15) * 8;
            #pragma unroll
            for (int p = 0; p < 8; ++p) {
                int row = r + p * 16;
                *(uint4*)(&Bs[row][c]) =
                    *(const uint4*)(fcwT + (size_t)(nc * 128 + row) * D_IN + c);
            }
        }
        __syncthreads();
        floatx4 acc[2][4] = {};
        #pragma unroll
        for (int ks = 0; ks < 4; ++ks) {
            short8 af[2], bf[4];
            #pragma unroll
            for (int mi = 0; mi < 2; ++mi)
                af[mi] = *(const short8*)(&As[wm + mi * 16 + l16][ks * 32 + q * 8]);
            #pragma unroll
            for (int ni = 0; ni < 4; ++ni)
                bf[ni] = *(const short8*)(&Bs[wn + ni * 16 + l16][ks * 32 + q * 8]);
            #pragma unroll
            for (int mi = 0; mi < 2; ++mi)
                #pragma unroll
                for (int ni = 0; ni < 4; ++ni)
                    acc[mi][ni] = __builtin_amdgcn_mfma_f32_16x16x32_bf16(af[mi], bf[ni], acc[mi][ni], 0, 0, 0);
        }
        #pragma unroll
        for (int mi = 0; mi < 2; ++mi)
            #pragma unroll
            for (int ni = 0; ni < 4; ++ni)
                #pragma unroll
                for (int r = 0; r < 4; ++r) {
                    int row = bm + wm + mi * 16 + q * 4 + r;
                    int col = nc * 128 + wn + ni * 16 + l16;
                    if (row < N_NODES) {
                        float v = fmaxf(acc[mi][ni][r] + fcb[col], 0.0f);
                        F[(size_t)row * D_HID + col] = f2bf(v);
                    }
                }
        __syncthreads();   // protect Bs before next chunk restage
    }
}

// ================= bf16 MFMA GEMM tile (GEMM2): BM=64,BN=128,BK=64 =========

#define GPAD 8
#define SM64_BYTES ((64 + 128) * (64 + GPAD) * 2)

template<int BIAS_RELU, int OUT_BF16>
__device__ __forceinline__ void gemm_tile64(char* smem,
    const unsigned short* __restrict__ A, int lda,
    const unsigned short* __restrict__ Bt, int ldb,
    const float* __restrict__ bias, void* __restrict__ Cout, int ldc,
    int M, int K, int bm, int bn)
{
    constexpr int BK = 64;
    typedef unsigned short Row[BK + GPAD];
    Row* As = (Row*)smem;
    Row* Bs = (Row*)(smem + 64 * (BK + GPAD) * 2);
    int tid = threadIdx.x;
    int lane = tid & 63, w = tid >> 6;
    int wm = (w >> 1) * 32, wn = (w & 1) * 64;
    int q = lane >> 4, l16 = lane & 15;
    floatx4 acc[2][4] = {};
    int ra = tid >> 2;            // A row 0..63
    int ca = (tid & 3) * 8;       // A col base; passes +0,+32
    int rb = tid >> 1;            // B row 0..127
    int cb = (tid & 1) * 8;       // B col base; passes +0,+16,+32,+48

    for (int k0 = 0; k0 < K; k0 += BK) {
        {
            int gr = bm + ra;
            const unsigned short* ap = A + (size_t)gr * lda + k0 + ca;
            #pragma unroll
            for (int p = 0; p < 2; ++p) {
                uint4 va = make_uint4(0u, 0u, 0u, 0u);
                if (gr < M) va = *(const uint4*)(ap + p * 32);
                *(uint4*)(&As[ra][ca + p * 32]) = va;
            }
        }
        {
            const unsigned short* bp = Bt + (size_t)(bn + rb) * ldb + k0 + cb;
            #pragma unroll
            for (int p = 0; p < 4; ++p)
                *(uint4*)(&Bs[rb][cb + p * 16]) = *(const uint4*)(bp + p * 16);
        }
        __syncthreads();
        #pragma unroll
        for (int ks = 0; ks < 2; ++ks) {
            short8 af[2], bf[4];
            #pragma unroll
            for (int mi = 0; mi < 2; ++mi)
                af[mi] = *(const short8*)(&As[wm + mi * 16 + l16][ks * 32 + q * 8]);
            #pragma unroll
            for (int ni = 0; ni < 4; ++ni)
                bf[ni] = *(const short8*)(&Bs[wn + ni * 16 + l16][ks * 32 + q * 8]);
            #pragma unroll
            for (int mi = 0; mi < 2; ++mi)
                #pragma unroll
                for (int ni = 0; ni < 4; ++ni)
                    acc[mi][ni] = __builtin_amdgcn_mfma_f32_16x16x32_bf16(af[mi], bf[ni], acc[mi][ni], 0, 0, 0);
        }
        __syncthreads();
    }

    #pragma unroll
    for (int mi = 0; mi < 2; ++mi) {
        #pragma unroll
        for (int ni = 0; ni < 4; ++ni) {
            #pragma unroll
            for (int r = 0; r < 4; ++r) {
                int row = bm + wm + mi * 16 + q * 4 + r;
                int col = bn + wn + ni * 16 + l16;
                if (row < M) {
                    float v = acc[mi][ni][r];
                    if (BIAS_RELU) v = fmaxf(v + bias[col], 0.0f);
                    if (OUT_BF16) ((unsigned short*)Cout)[(size_t)row * ldc + col] = f2bf(v);
                    else          ((float*)Cout)[(size_t)row * ldc + col] = v;
                }
            }
        }
    }
}

// ================= aggregate: wave per node (R0 form, measured 114 us) =====
// R1/R2 evidence: gather saturates the L2-miss service ceiling (~3.7 TB/s
// fetch) at this exact shape; deeper unroll (R2) and LDS fusion (R1) both
// regressed. Do not touch.

__device__ __forceinline__ void fmax_bf16x8(float* acc, const uint4& p) {
    const unsigned* a = (const unsigned*)&p;
    #pragma unroll
    for (int j = 0; j < 4; ++j) {
        unsigned u = a[j];
        acc[2 * j]     = fmaxf(acc[2 * j],     __uint_as_float(u << 16));
        acc[2 * j + 1] = fmaxf(acc[2 * j + 1], __uint_as_float(u & 0xffff0000u));
    }
}

__global__ __launch_bounds__(256)
void aggregate_kernel(const unsigned short* __restrict__ F,
                      const int* __restrict__ deg,
                      const int* __restrict__ edge_list,
                      unsigned short* __restrict__ concat) {
    int gw = (blockIdx.x * 256 + threadIdx.x) >> 6;
    if (gw >= N_NODES) return;
    int lane = threadIdx.x & 63;
    int d = deg[gw];
    d = d < CAP ? d : CAP;
    const int* el = edge_list + gw * CAP;
    float acc[8] = {0.f, 0.f, 0.f, 0.f, 0.f, 0.f, 0.f, 0.f};
    int i = 0;
    for (; i + 2 <= d; i += 2) {
        int t0 = el[i], t1 = el[i + 1];
        uint4 p0 = *(const uint4*)(F + (size_t)t0 * D_HID + lane * 8);
        uint4 p1 = *(const uint4*)(F + (size_t)t1 * D_HID + lane * 8);
        fmax_bf16x8(acc, p0);
        fmax_bf16x8(acc, p1);
    }
    if (i < d) {
        uint4 p0 = *(const uint4*)(F + (size_t)el[i] * D_HID + lane * 8);
        fmax_bf16x8(acc, p0);
    }
    unsigned out[4];
    #pragma unroll
    for (int j = 0; j < 4; ++j) {
        unsigned lo = __float_as_uint(acc[2 * j]) >> 16;          // exact: maxima of bf16 values
        unsigned hi = __float_as_uint(acc[2 * j + 1]) & 0xffff0000u;
        out[j] = lo | hi;
    }
    *(uint4*)(concat + (size_t)gw * CAT_DIM + D_IN + lane * 8) = *(uint4*)out;
}

// ================= GEMM2 ===================================================

#define GEMM2_MT 782   // ceil(50000/64)

__global__ __launch_bounds__(256)
void gemm2_kernel(const unsigned short* __restrict__ concat,
                  const unsigned short* __restrict__ WT,
                  float* __restrict__ out) {
    __shared__ char smem[SM64_BYTES];
    gemm_tile64<0, 0>(smem, concat, CAT_DIM, WT, CAT_DIM, nullptr, out, D_OUT,
                      N_NODES, CAT_DIM, blockIdx.x * 64, 0);
}

// ================= host launch =============================================

extern "C" void kernel_launch(void* const* d_in, const int* in_sizes, int n_in,
                              void* d_out, int out_size, void* d_ws, size_t ws_size,
                              hipStream_t stream) {
    const float* X    = (const float*)d_in[0];
    const float* fc_w = (const float*)d_in[1];
    const float* fc_b = (const float*)d_in[2];
    const float* Wm   = (const float*)d_in[3];
    const int*   adj  = (const int*)d_in[4];
    float* outp = (float*)d_out;

    char* ws = (char*)d_ws;
    size_t off = 0;
    auto alloc = [&](size_t bytes) -> void* {
        void* p = ws + off;
        off = (off + bytes + 255) & ~(size_t)255;
        return p;
    };
    unsigned short* concat = (unsigned short*)alloc((size_t)N_NODES * CAT_DIM * 2);
    unsigned short* F      = (unsigned short*)alloc((size_t)N_NODES * D_HID * 2);
    unsigned short* fcwT   = (unsigned short*)alloc((size_t)D_HID * D_IN * 2);
    unsigned short* WT     = (unsigned short*)alloc((size_t)D_OUT * CAT_DIM * 2);
    int* deg       = (int*)alloc((size_t)N_NODES * 4);
    int* edge_list = (int*)alloc((size_t)N_NODES * CAP * 4);

    hipMemsetAsync(deg, 0, (size_t)N_NODES * 4, stream);
    prep_hist_kernel<<<FUSED1_BLOCKS, 256, 0, stream>>>(X, fc_w, Wm, adj, concat,
                                                        fcwT, WT, deg, edge_list);
    gemm1_kernel<<<GEMM2_MT, 256, 0, stream>>>(concat, fcwT, fc_b, F);
    aggregate_kernel<<<(N_NODES * 64) / 256, 256, 0, stream>>>(F, deg, edge_list, concat);
    gemm2_kernel<<<GEMM2_MT, 256, 0, stream>>>(concat, WT, outp);
}

// Round 5
// 316.962 us; speedup vs baseline: 1.0460x; 1.0138x over previous
//
#include <hip/hip_runtime.h>
#include <hip/hip_bf16.h>

#define N_NODES 50000
#define N_EDGES 800000
#define D_IN 128
#define D_HID 512
#define D_OUT 128
#define CAT_DIM 640   // D_IN + D_HID
#define CAP 64        // per-node edge-bucket capacity (Poisson(16): P(>=64) ~ 1e-20)

typedef __attribute__((ext_vector_type(8))) short short8;
typedef __attribute__((ext_vector_type(4))) float floatx4;

__device__ __forceinline__ unsigned short f2bf(float f) {
    unsigned u = __float_as_uint(f);
    unsigned r = u + 0x7fffu + ((u >> 16) & 1u);   // RNE
    return (unsigned short)(r >> 16);
}

// convert 8 consecutive fp32 -> 8 bf16 (same bits as the old prep cast path)
__device__ __forceinline__ void cvt8(const float* __restrict__ src, unsigned short* o) {
    float4 v0 = *(const float4*)src;
    float4 v1 = *(const float4*)(src + 4);
    o[0] = f2bf(v0.x); o[1] = f2bf(v0.y); o[2] = f2bf(v0.z); o[3] = f2bf(v0.w);
    o[4] = f2bf(v1.x); o[5] = f2bf(v1.y); o[6] = f2bf(v1.z); o[7] = f2bf(v1.w);
}

// ================= prep0: weight transposes + deg zero =====================
// X is no longer pre-cast: GEMM1/GEMM2 read X fp32 and convert in-register
// during LDS staging (identical f2bf bits). Removes the 6250-block castX
// pass and the concat buffer entirely.

#define P0_FCW_BLOCKS 256   // 128*512 / 256
#define P0_W2_BLOCKS  320   // 640*128 / 256
#define P0_DEG_BLOCKS 196   // ceil(50000/256)
#define P0_BLOCKS (P0_FCW_BLOCKS + P0_W2_BLOCKS + P0_DEG_BLOCKS)

__global__ void prep0_kernel(const float* __restrict__ fcW, const float* __restrict__ Wm,
                             unsigned short* __restrict__ fcwT,
                             unsigned short* __restrict__ WT,
                             int* __restrict__ deg) {
    int b = blockIdx.x, tid = threadIdx.x;
    if (b < P0_FCW_BLOCKS) {
        int idx = b * 256 + tid;               // 128*512
        int k = idx >> 9;
        int n = idx & (D_HID - 1);
        fcwT[n * D_IN + k] = f2bf(fcW[idx]);
        return;
    }
    b -= P0_FCW_BLOCKS;
    if (b < P0_W2_BLOCKS) {
        int idx = b * 256 + tid;               // 640*128
        int k = idx >> 7;
        int n = idx & (D_OUT - 1);
        WT[n * CAT_DIM + k] = f2bf(Wm[idx]);
        return;
    }
    b -= P0_W2_BLOCKS;
    int idx = b * 256 + tid;
    if (idx < N_NODES) deg[idx] = 0;
}

// ================= hist: standalone (decomposition measurement) ============

__device__ __forceinline__ void hist_edges(const int* __restrict__ adj, int s, int e0,
                                           int* __restrict__ deg, int* __restrict__ edge_list) {
    int src0, src1, trg0, trg1;
    if (s == 2) {   // int64: edges e0,e0+1 -> adj dwords [2e0 .. 2e0+3], coalesced
        int4 vs = *(const int4*)(adj + 2 * (size_t)e0);
        int4 vt = *(const int4*)(adj + 2 * ((size_t)N_EDGES + e0));
        src0 = vs.x; src1 = vs.z;
        trg0 = vt.x; trg1 = vt.z;
    } else {        // int32
        int2 vs = *(const int2*)(adj + e0);
        int2 vt = *(const int2*)(adj + N_EDGES + e0);
        src0 = vs.x; src1 = vs.y;
        trg0 = vt.x; trg1 = vt.y;
    }
    int p0 = atomicAdd(&deg[src0], 1);
    if (p0 < CAP) edge_list[src0 * CAP + p0] = trg0;
    int p1 = atomicAdd(&deg[src1], 1);
    if (p1 < CAP) edge_list[src1 * CAP + p1] = trg1;
}

#define HIST_BLOCKS 1563   // ceil((N_EDGES/2)/256)

__global__ __launch_bounds__(256)
void hist_kernel(const int* __restrict__ adj,
                 int* __restrict__ deg, int* __restrict__ edge_list) {
    int tid = threadIdx.x;
    // per-wave dtype detect: int64 iff high dwords of first 64 ids all zero
    int v = adj[2 * (tid & 63) + 1];
    int s = (__ballot(v != 0) == 0ULL) ? 2 : 1;
    int e0 = (blockIdx.x * 256 + tid) * 2;
    if (e0 < N_EDGES) hist_edges(adj, s, e0, deg, edge_list);
}

// ================= GEMM1: A staged once from X fp32, B-chunk loop ==========
// K = 128 (no K-loop). BM=64, full N=512 per block, 782 blocks. A-tile read
// once from X fp32 (25.6 MB) with in-register bf16 convert; B chunks of 128
// cols from L2-resident fcwT (128 KB). LDS 52224 B -> 3 blocks/CU.

#define G1_PAD 8

__global__ __launch_bounds__(256)
void gemm1_kernel(const float* __restrict__ X,
                  const unsigned short* __restrict__ fcwT,
                  const float* __restrict__ fcb,
                  unsigned short* __restrict__ F) {
    __shared__ unsigned short As[64][D_IN + G1_PAD];
    __shared__ unsigned short Bs[128][D_IN + G1_PAD];
    int tid = threadIdx.x;
    int lane = tid & 63, w = tid >> 6;
    int bm = blockIdx.x * 64;
    {   // stage A once: 4 passes x (16 rows x 128 cols), fp32 -> bf16
        int r = tid >> 4;
        int c = (tid & 15) * 8;
        #pragma unroll
        for (int p = 0; p < 4; ++p) {
            int row = r + p * 16;
            int gr = bm + row;
            unsigned short o[8] = {0, 0, 0, 0, 0, 0, 0, 0};
            if (gr < N_NODES) cvt8(X + (size_t)gr * D_IN + c, o);
            *(uint4*)(&As[row][c]) = *(const uint4*)o;
        }
    }
    int wm = (w >> 1) * 32, wn = (w & 1) * 64;
    int q = lane >> 4, l16 = lane & 15;
    for (int nc = 0; nc < 4; ++nc) {
        {   // stage B chunk: fcwT rows [nc*128, nc*128+128)
            int r = tid >> 4;
            int c = (tid & 15) * 8;
            #pragma unroll
            for (int p = 0; p < 8; ++p) {
                int row = r + p * 16;
                *(uint4*)(&Bs[row][c]) =
                    *(const uint4*)(fcwT + (size_t)(nc * 128 + row) * D_IN + c);
            }
        }
        __syncthreads();
        floatx4 acc[2][4] = {};
        #pragma unroll
        for (int ks = 0; ks < 4; ++ks) {
            short8 af[2], bf[4];
            #pragma unroll
            for (int mi = 0; mi < 2; ++mi)
                af[mi] = *(const short8*)(&As[wm + mi * 16 + l16][ks * 32 + q * 8]);
            #pragma unroll
            for (int ni = 0; ni < 4; ++ni)
                bf[ni] = *(const short8*)(&Bs[wn + ni * 16 + l16][ks * 32 + q * 8]);
            #pragma unroll
            for (int mi = 0; mi < 2; ++mi)
                #pragma unroll
                for (int ni = 0; ni < 4; ++ni)
                    acc[mi][ni] = __builtin_amdgcn_mfma_f32_16x16x32_bf16(af[mi], bf[ni], acc[mi][ni], 0, 0, 0);
        }
        #pragma unroll
        for (int mi = 0; mi < 2; ++mi)
            #pragma unroll
            for (int ni = 0; ni < 4; ++ni)
                #pragma unroll
                for (int r = 0; r < 4; ++r) {
                    int row = bm + wm + mi * 16 + q * 4 + r;
                    int col = nc * 128 + wn + ni * 16 + l16;
                    if (row < N_NODES) {
                        float v = fmaxf(acc[mi][ni][r] + fcb[col], 0.0f);
                        F[(size_t)row * D_HID + col] = f2bf(v);
                    }
                }
        __syncthreads();   // protect Bs before next chunk restage
    }
}

// ================= aggregate: wave per node (R0 form, measured 114 us) =====
// R1/R2 evidence: gather saturates the L2-miss service ceiling (~3.7 TB/s
// fetch) at this exact shape; deeper unroll (R2) and LDS fusion (R1) both
// regressed. Only change vs R0: output is a dedicated agg[N][512] buffer
// (contiguous 1 KB row per wave, same uint4 store pattern).

__device__ __forceinline__ void fmax_bf16x8(float* acc, const uint4& p) {
    const unsigned* a = (const unsigned*)&p;
    #pragma unroll
    for (int j = 0; j < 4; ++j) {
        unsigned u = a[j];
        acc[2 * j]     = fmaxf(acc[2 * j],     __uint_as_float(u << 16));
        acc[2 * j + 1] = fmaxf(acc[2 * j + 1], __uint_as_float(u & 0xffff0000u));
    }
}

__global__ __launch_bounds__(256)
void aggregate_kernel(const unsigned short* __restrict__ F,
                      const int* __restrict__ deg,
                      const int* __restrict__ edge_list,
                      unsigned short* __restrict__ agg) {
    int gw = (blockIdx.x * 256 + threadIdx.x) >> 6;
    if (gw >= N_NODES) return;
    int lane = threadIdx.x & 63;
    int d = deg[gw];
    d = d < CAP ? d : CAP;
    const int* el = edge_list + gw * CAP;
    float acc[8] = {0.f, 0.f, 0.f, 0.f, 0.f, 0.f, 0.f, 0.f};
    int i = 0;
    for (; i + 2 <= d; i += 2) {
        int t0 = el[i], t1 = el[i + 1];
        uint4 p0 = *(const uint4*)(F + (size_t)t0 * D_HID + lane * 8);
        uint4 p1 = *(const uint4*)(F + (size_t)t1 * D_HID + lane * 8);
        fmax_bf16x8(acc, p0);
        fmax_bf16x8(acc, p1);
    }
    if (i < d) {
        uint4 p0 = *(const uint4*)(F + (size_t)el[i] * D_HID + lane * 8);
        fmax_bf16x8(acc, p0);
    }
    unsigned out[4];
    #pragma unroll
    for (int j = 0; j < 4; ++j) {
        unsigned lo = __float_as_uint(acc[2 * j]) >> 16;          // exact: maxima of bf16 values
        unsigned hi = __float_as_uint(acc[2 * j + 1]) & 0xffff0000u;
        out[j] = lo | hi;
    }
    *(uint4*)(agg + (size_t)gw * D_HID + lane * 8) = *(uint4*)out;
}

// ================= GEMM2: A = [X fp32 | agg bf16], B = WT ==================
// BM=64, BN=128 (full D_OUT), BK=64, 10 K-steps. k0 in {0,64}: A staged from
// X fp32 with in-register convert (same bits as old concat path); k0 >= 128:
// from agg bf16. LDS 27648 B -> 5 blocks/CU.

#define GPAD 8
#define GEMM_MT 782   // ceil(50000/64)

__global__ __launch_bounds__(256)
void gemm2_kernel(const float* __restrict__ X,
                  const unsigned short* __restrict__ agg,
                  const unsigned short* __restrict__ WT,
                  float* __restrict__ out) {
    __shared__ unsigned short As[64][64 + GPAD];
    __shared__ unsigned short Bs[128][64 + GPAD];
    int tid = threadIdx.x;
    int lane = tid & 63, w = tid >> 6;
    int wm = (w >> 1) * 32, wn = (w & 1) * 64;
    int q = lane >> 4, l16 = lane & 15;
    int bm = blockIdx.x * 64;
    floatx4 acc[2][4] = {};
    int ra = tid >> 2;            // A row 0..63
    int ca = (tid & 3) * 8;       // A col base; passes +0,+32
    int rb = tid >> 1;            // B row 0..127
    int cb = (tid & 1) * 8;       // B col base; passes +0,+16,+32,+48

    for (int k0 = 0; k0 < CAT_DIM; k0 += 64) {
        {
            int gr = bm + ra;
            #pragma unroll
            for (int p = 0; p < 2; ++p) {
                int col = k0 + ca + p * 32;
                unsigned short o[8] = {0, 0, 0, 0, 0, 0, 0, 0};
                if (gr < N_NODES) {
                    if (col < D_IN) cvt8(X + (size_t)gr * D_IN + col, o);
                    else *(uint4*)o = *(const uint4*)(agg + (size_t)gr * D_HID + (col - D_IN));
                }
                *(uint4*)(&As[ra][ca + p * 32]) = *(const uint4*)o;
            }
        }
        {
            const unsigned short* bp = WT + (size_t)rb * CAT_DIM + k0 + cb;
            #pragma unroll
            for (int p = 0; p < 4; ++p)
                *(uint4*)(&Bs[rb][cb + p * 16]) = *(const uint4*)(bp + p * 16);
        }
        __syncthreads();
        #pragma unroll
        for (int ks = 0; ks < 2; ++ks) {
            short8 af[2], bf[4];
            #pragma unroll
            for (int mi = 0; mi < 2; ++mi)
                af[mi] = *(const short8*)(&As[wm + mi * 16 + l16][ks * 32 + q * 8]);
            #pragma unroll
            for (int ni = 0; ni < 4; ++ni)
                bf[ni] = *(const short8*)(&Bs[wn + ni * 16 + l16][ks * 32 + q * 8]);
            #pragma unroll
            for (int mi = 0; mi < 2; ++mi)
                #pragma unroll
                for (int ni = 0; ni < 4; ++ni)
                    acc[mi][ni] = __builtin_amdgcn_mfma_f32_16x16x32_bf16(af[mi], bf[ni], acc[mi][ni], 0, 0, 0);
        }
        __syncthreads();
    }

    #pragma unroll
    for (int mi = 0; mi < 2; ++mi)
        #pragma unroll
        for (int ni = 0; ni < 4; ++ni)
            #pragma unroll
            for (int r = 0; r < 4; ++r) {
                int row = bm + wm + mi * 16 + q * 4 + r;
                int col = wn + ni * 16 + l16;
                if (row < N_NODES)
                    out[(size_t)row * D_OUT + col] = acc[mi][ni][r];
            }
}

// ================= host launch =============================================

extern "C" void kernel_launch(void* const* d_in, const int* in_sizes, int n_in,
                              void* d_out, int out_size, void* d_ws, size_t ws_size,
                              hipStream_t stream) {
    const float* X    = (const float*)d_in[0];
    const float* fc_w = (const float*)d_in[1];
    const float* fc_b = (const float*)d_in[2];
    const float* Wm   = (const float*)d_in[3];
    const int*   adj  = (const int*)d_in[4];
    float* outp = (float*)d_out;

    char* ws = (char*)d_ws;
    size_t off = 0;
    auto alloc = [&](size_t bytes) -> void* {
        void* p = ws + off;
        off = (off + bytes + 255) & ~(size_t)255;
        return p;
    };
    unsigned short* agg    = (unsigned short*)alloc((size_t)N_NODES * D_HID * 2);
    unsigned short* F      = (unsigned short*)alloc((size_t)N_NODES * D_HID * 2);
    unsigned short* fcwT   = (unsigned short*)alloc((size_t)D_HID * D_IN * 2);
    unsigned short* WT     = (unsigned short*)alloc((size_t)D_OUT * CAT_DIM * 2);
    int* deg       = (int*)alloc((size_t)N_NODES * 4);
    int* edge_list = (int*)alloc((size_t)N_NODES * CAP * 4);

    prep0_kernel<<<P0_BLOCKS, 256, 0, stream>>>(fc_w, Wm, fcwT, WT, deg);
    hist_kernel<<<HIST_BLOCKS, 256, 0, stream>>>(adj, deg, edge_list);
    gemm1_kernel<<<GEMM_MT, 256, 0, stream>>>(X, fcwT, fc_b, F);
    aggregate_kernel<<<(N_NODES * 64) / 256, 256, 0, stream>>>(F, deg, edge_list, agg);
    gemm2_kernel<<<GEMM_MT, 256, 0, stream>>>(X, agg, WT, outp);
}

// Round 6
// 289.967 us; speedup vs baseline: 1.1433x; 1.0931x over previous
//
#include <hip/hip_runtime.h>
#include <hip/hip_bf16.h>

#define N_NODES 50000
#define N_EDGES 800000
#define D_IN 128
#define D_HID 512
#define D_OUT 128
#define CAT_DIM 640   // D_IN + D_HID
#define CAP 64        // per-node edge-bucket capacity (Poisson(16): P(>=64) ~ 1e-20)

typedef __attribute__((ext_vector_type(8))) short short8;
typedef __attribute__((ext_vector_type(4))) float floatx4;

__device__ __forceinline__ unsigned short f2bf(float f) {
    unsigned u = __float_as_uint(f);
    unsigned r = u + 0x7fffu + ((u >> 16) & 1u);   // RNE
    return (unsigned short)(r >> 16);
}

// convert 8 consecutive fp32 -> 8 bf16 (same bits as a pre-cast pass)
__device__ __forceinline__ void cvt8(const float* __restrict__ src, unsigned short* o) {
    float4 v0 = *(const float4*)src;
    float4 v1 = *(const float4*)(src + 4);
    o[0] = f2bf(v0.x); o[1] = f2bf(v0.y); o[2] = f2bf(v0.z); o[3] = f2bf(v0.w);
    o[4] = f2bf(v1.x); o[5] = f2bf(v1.y); o[6] = f2bf(v1.z); o[7] = f2bf(v1.w);
}

// ================= prep0: weight transposes + deg zero (~6 us) =============

#define P0_FCW_BLOCKS 256   // 128*512 / 256
#define P0_W2_BLOCKS  320   // 640*128 / 256
#define P0_DEG_BLOCKS 196   // ceil(50000/256)
#define P0_BLOCKS (P0_FCW_BLOCKS + P0_W2_BLOCKS + P0_DEG_BLOCKS)

__global__ void prep0_kernel(const float* __restrict__ fcW, const float* __restrict__ Wm,
                             unsigned short* __restrict__ fcwT,
                             unsigned short* __restrict__ WT,
                             int* __restrict__ deg) {
    int b = blockIdx.x, tid = threadIdx.x;
    if (b < P0_FCW_BLOCKS) {
        int idx = b * 256 + tid;               // 128*512
        int k = idx >> 9;
        int n = idx & (D_HID - 1);
        fcwT[n * D_IN + k] = f2bf(fcW[idx]);
        return;
    }
    b -= P0_FCW_BLOCKS;
    if (b < P0_W2_BLOCKS) {
        int idx = b * 256 + tid;               // 640*128
        int k = idx >> 7;
        int n = idx & (D_OUT - 1);
        WT[n * CAT_DIM + k] = f2bf(Wm[idx]);
        return;
    }
    b -= P0_W2_BLOCKS;
    int idx = b * 256 + tid;
    if (idx < N_NODES) deg[idx] = 0;
}

// ================= hist (device fn) ========================================

__device__ __forceinline__ void hist_edges(const int* __restrict__ adj, int s, int e0,
                                           int* __restrict__ deg, int* __restrict__ edge_list) {
    int src0, src1, trg0, trg1;
    if (s == 2) {   // int64: edges e0,e0+1 -> adj dwords [2e0 .. 2e0+3], coalesced
        int4 vs = *(const int4*)(adj + 2 * (size_t)e0);
        int4 vt = *(const int4*)(adj + 2 * ((size_t)N_EDGES + e0));
        src0 = vs.x; src1 = vs.z;
        trg0 = vt.x; trg1 = vt.z;
    } else {        // int32
        int2 vs = *(const int2*)(adj + e0);
        int2 vt = *(const int2*)(adj + N_EDGES + e0);
        src0 = vs.x; src1 = vs.y;
        trg0 = vt.x; trg1 = vt.y;
    }
    int p0 = atomicAdd(&deg[src0], 1);
    if (p0 < CAP) edge_list[src0 * CAP + p0] = trg0;
    int p1 = atomicAdd(&deg[src1], 1);
    if (p1 < CAP) edge_list[src1 * CAP + p1] = trg1;
}

// ================= fused mid: hist blocks ∥ gemm1 blocks ===================
// R0 proved hist (latency-bound scatter, ~100 us standalone) and GEMM1
// (~50 us) overlap to ~max: fuse as disjoint block ranges, hist first.
// Branch is blockIdx-uniform -> barriers safe (hist blocks return early).
// gemm1: BM=64 rows, A staged ONCE from X fp32 (in-register bf16 cvt, read
// once: 25.6 MB); B chunks of 64 fcwT rows (L2-resident). LDS = (64+64) x
// 136 x 2 = 34816 B -> 4 blocks/CU (16 waves/CU for hist blocks; the 52 KB
// variant would cap hist at 12 -- R1 showed this class of kernel loses BW
// with occupancy).

#define HIST_BLOCKS 1563   // ceil((N_EDGES/2)/256)
#define GEMM_MT      782   // ceil(50000/64)
#define G1_PAD 8

__global__ __launch_bounds__(256)
void mid_kernel(const int* __restrict__ adj,
                int* __restrict__ deg, int* __restrict__ edge_list,
                const float* __restrict__ X,
                const unsigned short* __restrict__ fcwT,
                const float* __restrict__ fcb,
                unsigned short* __restrict__ F) {
    int tid = threadIdx.x;
    if (blockIdx.x < HIST_BLOCKS) {
        // per-wave dtype detect: int64 iff high dwords of first 64 ids all zero
        int v = adj[2 * (tid & 63) + 1];
        int s = (__ballot(v != 0) == 0ULL) ? 2 : 1;
        int e0 = (blockIdx.x * 256 + tid) * 2;
        if (e0 < N_EDGES) hist_edges(adj, s, e0, deg, edge_list);
        return;
    }
    __shared__ unsigned short As[64][D_IN + G1_PAD];
    __shared__ unsigned short Bs[64][D_IN + G1_PAD];
    int lane = tid & 63, w = tid >> 6;
    int bm = (blockIdx.x - HIST_BLOCKS) * 64;
    {   // stage A once: 4 passes x (16 rows x 128 cols), fp32 -> bf16
        int r = tid >> 4;
        int c = (tid & 15) * 8;
        #pragma unroll
        for (int p = 0; p < 4; ++p) {
            int row = r + p * 16;
            int gr = bm + row;
            unsigned short o[8] = {0, 0, 0, 0, 0, 0, 0, 0};
            if (gr < N_NODES) cvt8(X + (size_t)gr * D_IN + c, o);
            *(uint4*)(&As[row][c]) = *(const uint4*)o;
        }
    }
    int wm = (w >> 1) * 32, wn = (w & 1) * 32;
    int q = lane >> 4, l16 = lane & 15;
    for (int nc = 0; nc < 8; ++nc) {
        {   // stage B chunk: fcwT rows [nc*64, nc*64+64)
            int r = tid >> 4;
            int c = (tid & 15) * 8;
            #pragma unroll
            for (int p = 0; p < 4; ++p) {
                int row = r + p * 16;
                *(uint4*)(&Bs[row][c]) =
                    *(const uint4*)(fcwT + (size_t)(nc * 64 + row) * D_IN + c);
            }
        }
        __syncthreads();
        floatx4 acc[2][2] = {};
        #pragma unroll
        for (int ks = 0; ks < 4; ++ks) {
            short8 af[2], bf[2];
            #pragma unroll
            for (int mi = 0; mi < 2; ++mi)
                af[mi] = *(const short8*)(&As[wm + mi * 16 + l16][ks * 32 + q * 8]);
            #pragma unroll
            for (int ni = 0; ni < 2; ++ni)
                bf[ni] = *(const short8*)(&Bs[wn + ni * 16 + l16][ks * 32 + q * 8]);
            #pragma unroll
            for (int mi = 0; mi < 2; ++mi)
                #pragma unroll
                for (int ni = 0; ni < 2; ++ni)
                    acc[mi][ni] = __builtin_amdgcn_mfma_f32_16x16x32_bf16(af[mi], bf[ni], acc[mi][ni], 0, 0, 0);
        }
        #pragma unroll
        for (int mi = 0; mi < 2; ++mi)
            #pragma unroll
            for (int ni = 0; ni < 2; ++ni)
                #pragma unroll
                for (int r = 0; r < 4; ++r) {
                    int row = bm + wm + mi * 16 + q * 4 + r;
                    int col = nc * 64 + wn + ni * 16 + l16;
                    if (row < N_NODES) {
                        float v = fmaxf(acc[mi][ni][r] + fcb[col], 0.0f);
                        F[(size_t)row * D_HID + col] = f2bf(v);
                    }
                }
        __syncthreads();   // protect Bs before next chunk restage
    }
}

// ================= aggregate: wave per node (R0 form, measured 114 us) =====
// Floor established R1/R2/R5: FETCH ~377 MB = 8 XCDs x F(51.2 MB) compulsory
// cross-XCD duplication at the L3 random-granule service rate (~3.5 TB/s).
// Occupancy changes, unrolls, and fusion all regress. Do not touch.

__device__ __forceinline__ void fmax_bf16x8(float* acc, const uint4& p) {
    const unsigned* a = (const unsigned*)&p;
    #pragma unroll
    for (int j = 0; j < 4; ++j) {
        unsigned u = a[j];
        acc[2 * j]     = fmaxf(acc[2 * j],     __uint_as_float(u << 16));
        acc[2 * j + 1] = fmaxf(acc[2 * j + 1], __uint_as_float(u & 0xffff0000u));
    }
}

__global__ __launch_bounds__(256)
void aggregate_kernel(const unsigned short* __restrict__ F,
                      const int* __restrict__ deg,
                      const int* __restrict__ edge_list,
                      unsigned short* __restrict__ agg) {
    int gw = (blockIdx.x * 256 + threadIdx.x) >> 6;
    if (gw >= N_NODES) return;
    int lane = threadIdx.x & 63;
    int d = deg[gw];
    d = d < CAP ? d : CAP;
    const int* el = edge_list + gw * CAP;
    float acc[8] = {0.f, 0.f, 0.f, 0.f, 0.f, 0.f, 0.f, 0.f};
    int i = 0;
    for (; i + 2 <= d; i += 2) {
        int t0 = el[i], t1 = el[i + 1];
        uint4 p0 = *(const uint4*)(F + (size_t)t0 * D_HID + lane * 8);
        uint4 p1 = *(const uint4*)(F + (size_t)t1 * D_HID + lane * 8);
        fmax_bf16x8(acc, p0);
        fmax_bf16x8(acc, p1);
    }
    if (i < d) {
        uint4 p0 = *(const uint4*)(F + (size_t)el[i] * D_HID + lane * 8);
        fmax_bf16x8(acc, p0);
    }
    unsigned out[4];
    #pragma unroll
    for (int j = 0; j < 4; ++j) {
        unsigned lo = __float_as_uint(acc[2 * j]) >> 16;          // exact: maxima of bf16 values
        unsigned hi = __float_as_uint(acc[2 * j + 1]) & 0xffff0000u;
        out[j] = lo | hi;
    }
    *(uint4*)(agg + (size_t)gw * D_HID + lane * 8) = *(uint4*)out;
}

// ================= GEMM2: A = [X fp32 | agg bf16], B = WT ==================
// BM=64, BN=128 (full D_OUT), BK=64, 10 K-steps. k0 in {0,64}: A staged from
// X fp32 with in-register convert; k0 >= 128: from agg bf16. LDS 27648 B.

#define GPAD 8

__global__ __launch_bounds__(256)
void gemm2_kernel(const float* __restrict__ X,
                  const unsigned short* __restrict__ agg,
                  const unsigned short* __restrict__ WT,
                  float* __restrict__ out) {
    __shared__ unsigned short As[64][64 + GPAD];
    __shared__ unsigned short Bs[128][64 + GPAD];
    int tid = threadIdx.x;
    int lane = tid & 63, w = tid >> 6;
    int wm = (w >> 1) * 32, wn = (w & 1) * 64;
    int q = lane >> 4, l16 = lane & 15;
    int bm = blockIdx.x * 64;
    floatx4 acc[2][4] = {};
    int ra = tid >> 2;            // A row 0..63
    int ca = (tid & 3) * 8;       // A col base; passes +0,+32
    int rb = tid >> 1;            // B row 0..127
    int cb = (tid & 1) * 8;       // B col base; passes +0,+16,+32,+48

    for (int k0 = 0; k0 < CAT_DIM; k0 += 64) {
        {
            int gr = bm + ra;
            #pragma unroll
            for (int p = 0; p < 2; ++p) {
                int col = k0 + ca + p * 32;
                unsigned short o[8] = {0, 0, 0, 0, 0, 0, 0, 0};
                if (gr < N_NODES) {
                    if (col < D_IN) cvt8(X + (size_t)gr * D_IN + col, o);
                    else *(uint4*)o = *(const uint4*)(agg + (size_t)gr * D_HID + (col - D_IN));
                }
                *(uint4*)(&As[ra][ca + p * 32]) = *(const uint4*)o;
            }
        }
        {
            const unsigned short* bp = WT + (size_t)rb * CAT_DIM + k0 + cb;
            #pragma unroll
            for (int p = 0; p < 4; ++p)
                *(uint4*)(&Bs[rb][cb + p * 16]) = *(const uint4*)(bp + p * 16);
        }
        __syncthreads();
        #pragma unroll
        for (int ks = 0; ks < 2; ++ks) {
            short8 af[2], bf[4];
            #pragma unroll
            for (int mi = 0; mi < 2; ++mi)
                af[mi] = *(const short8*)(&As[wm + mi * 16 + l16][ks * 32 + q * 8]);
            #pragma unroll
            for (int ni = 0; ni < 4; ++ni)
                bf[ni] = *(const short8*)(&Bs[wn + ni * 16 + l16][ks * 32 + q * 8]);
            #pragma unroll
            for (int mi = 0; mi < 2; ++mi)
                #pragma unroll
                for (int ni = 0; ni < 4; ++ni)
                    acc[mi][ni] = __builtin_amdgcn_mfma_f32_16x16x32_bf16(af[mi], bf[ni], acc[mi][ni], 0, 0, 0);
        }
        __syncthreads();
    }

    #pragma unroll
    for (int mi = 0; mi < 2; ++mi)
        #pragma unroll
        for (int ni = 0; ni < 4; ++ni)
            #pragma unroll
            for (int r = 0; r < 4; ++r) {
                int row = bm + wm + mi * 16 + q * 4 + r;
                int col = wn + ni * 16 + l16;
                if (row < N_NODES)
                    out[(size_t)row * D_OUT + col] = acc[mi][ni][r];
            }
}

// ================= host launch =============================================

extern "C" void kernel_launch(void* const* d_in, const int* in_sizes, int n_in,
                              void* d_out, int out_size, void* d_ws, size_t ws_size,
                              hipStream_t stream) {
    const float* X    = (const float*)d_in[0];
    const float* fc_w = (const float*)d_in[1];
    const float* fc_b = (const float*)d_in[2];
    const float* Wm   = (const float*)d_in[3];
    const int*   adj  = (const int*)d_in[4];
    float* outp = (float*)d_out;

    char* ws = (char*)d_ws;
    size_t off = 0;
    auto alloc = [&](size_t bytes) -> void* {
        void* p = ws + off;
        off = (off + bytes + 255) & ~(size_t)255;
        return p;
    };
    unsigned short* agg    = (unsigned short*)alloc((size_t)N_NODES * D_HID * 2);
    unsigned short* F      = (unsigned short*)alloc((size_t)N_NODES * D_HID * 2);
    unsigned short* fcwT   = (unsigned short*)alloc((size_t)D_HID * D_IN * 2);
    unsigned short* WT     = (unsigned short*)alloc((size_t)D_OUT * CAT_DIM * 2);
    int* deg       = (int*)alloc((size_t)N_NODES * 4);
    int* edge_list = (int*)alloc((size_t)N_NODES * CAP * 4);

    prep0_kernel<<<P0_BLOCKS, 256, 0, stream>>>(fc_w, Wm, fcwT, WT, deg);
    mid_kernel<<<HIST_BLOCKS + GEMM_MT, 256, 0, stream>>>(adj, deg, edge_list,
                                                          X, fcwT, fc_b, F);
    aggregate_kernel<<<(N_NODES * 64) / 256, 256, 0, stream>>>(F, deg, edge_list, agg);
    gemm2_kernel<<<GEMM_MT, 256, 0, stream>>>(X, agg, WT, outp);
}